// Round 3
// baseline (612.094 us; speedup 1.0000x reference)
//
#include <hip/hip_runtime.h>
#include <hip/hip_bf16.h>

typedef unsigned short u16;
typedef __bf16 bf16x8 __attribute__((ext_vector_type(8)));
typedef unsigned short u16x8 __attribute__((ext_vector_type(8)));
typedef unsigned short u16x4 __attribute__((ext_vector_type(4)));
typedef float f32x4 __attribute__((ext_vector_type(4)));

#define B_ 8
#define T_ 2048
#define E_ 1024
#define H_ 1024
#define M_ (B_ * T_)   // 16384

__device__ inline u16 f2bf(float f) {
    __bf16 h = (__bf16)f;
    return __builtin_bit_cast(u16, h);
}

__device__ inline bf16x8 load_frag(const u16* p) {
    u16x8 u = *(const u16x8*)p;
    return __builtin_bit_cast(bf16x8, u);
}

__device__ inline void gload_lds16(const u16* g, u16* l) {
    __builtin_amdgcn_global_load_lds(
        (__attribute__((address_space(1))) unsigned int*)(g),
        (__attribute__((address_space(3))) unsigned int*)(l), 16, 0, 0);
}

// ---------------- cast fp32 -> bf16 ----------------
__global__ void castk(const float* __restrict__ in, u16* __restrict__ out, int n) {
    int i = (blockIdx.x * blockDim.x + threadIdx.x) * 4;
    if (i < n) {
        f32x4 f = *(const f32x4*)(in + i);
        u16x4 u;
        u[0] = f2bf(f[0]); u[1] = f2bf(f[1]); u[2] = f2bf(f[2]); u[3] = f2bf(f[3]);
        *(u16x4*)(out + i) = u;
    }
}

// ---------------- fused QKV GEMM ----------------
// A: [16384][1024] bf16, W: [3072][1024] bf16 ([Wq;Wk;Wv], K-major rows)
// qo: row-major [M][1024]
// ko: fragment-native KF [b][s/16][h/32][q=(h>>3)&3][si=s&15][hj=h&7]
// vo: fragment-native VF [b][h/16][s/32][q=(s>>3)&3][hi=h&15][si=s&7]
__global__ __launch_bounds__(256) void gemm_qkv(const u16* __restrict__ A,
                                                const u16* __restrict__ W,
                                                u16* __restrict__ qo,
                                                u16* __restrict__ ko,
                                                u16* __restrict__ vo) {
    const int bm = blockIdx.x, bn = blockIdx.y;
    const int tid = threadIdx.x;
    const int w = tid >> 6, lane = tid & 63, quad = lane >> 4, l16 = lane & 15;
    const int wr = w & 1, wc = w >> 1;

    __shared__ u16 smem[128 * 128];   // 32 KB: As(16K) + Bs(16K), later C-tile
    u16* As = smem;
    u16* Bs = smem + 128 * 64;

    f32x4 acc[16] = {};

    const u16* Ab = A + (size_t)(bm * 128) * E_;
    const u16* Wb = W + (size_t)(bn * 128) * E_;

    for (int kk = 0; kk < E_; kk += 64) {
        __syncthreads();
#pragma unroll
        for (int i = 0; i < 4; i++) {
            int chunk = i * 256 + tid;       // 0..1023
            int row = chunk >> 3, cc = chunk & 7;
            int ccs = cc ^ (row & 7);
            gload_lds16(Ab + (size_t)row * E_ + kk + ccs * 8, &As[chunk * 8]);
            gload_lds16(Wb + (size_t)row * E_ + kk + ccs * 8, &Bs[chunk * 8]);
        }
        __syncthreads();
#pragma unroll
        for (int k2 = 0; k2 < 2; k2++) {
            bf16x8 af[4], bf[4];
#pragma unroll
            for (int ri = 0; ri < 4; ri++) {
                int m = wr * 64 + ri * 16 + l16;
                int slot = m * 8 + ((k2 * 4 + quad) ^ (m & 7));
                af[ri] = load_frag(&As[slot * 8]);
            }
#pragma unroll
            for (int ci = 0; ci < 4; ci++) {
                int n = wc * 64 + ci * 16 + l16;
                int slot = n * 8 + ((k2 * 4 + quad) ^ (n & 7));
                bf[ci] = load_frag(&Bs[slot * 8]);
            }
#pragma unroll
            for (int ri = 0; ri < 4; ri++)
#pragma unroll
                for (int ci = 0; ci < 4; ci++)
                    acc[ri * 4 + ci] = __builtin_amdgcn_mfma_f32_16x16x32_bf16(
                        af[ri], bf[ci], acc[ri * 4 + ci], 0, 0, 0);
        }
    }

    // ---- epilogue: acc -> LDS (bf16, swizzled) -> coalesced stores ----
    __syncthreads();
    if (bn < 16) {
        // [m][n] orientation: elem(m,n) @ m*128 + ((n>>3 ^ (m&15))<<3) + (n&7)
#pragma unroll
        for (int ri = 0; ri < 4; ri++)
#pragma unroll
            for (int ci = 0; ci < 4; ci++) {
                int n = wc * 64 + ci * 16 + l16;
#pragma unroll
                for (int r = 0; r < 4; r++) {
                    int m = wr * 64 + ri * 16 + quad * 4 + r;
                    smem[m * 128 + (((n >> 3) ^ (m & 15)) << 3) + (n & 7)] =
                        f2bf(acc[ri * 4 + ci][r]);
                }
            }
    } else {
        // [n][m] orientation, pack 4 consecutive m (b64 writes)
#pragma unroll
        for (int ri = 0; ri < 4; ri++)
#pragma unroll
            for (int ci = 0; ci < 4; ci++) {
                int n = wc * 64 + ci * 16 + l16;
                int m0 = wr * 64 + ri * 16 + quad * 4;
                u16x4 pk;
#pragma unroll
                for (int r = 0; r < 4; r++) pk[r] = f2bf(acc[ri * 4 + ci][r]);
                *(u16x4*)&smem[n * 128 + (((m0 >> 3) ^ (n & 15)) << 3) + (m0 & 7)] = pk;
            }
    }
    __syncthreads();

    const int b = bm >> 4;
    if (bn < 8) {
#pragma unroll
        for (int i = 0; i < 8; i++) {
            int c = i * 256 + tid;
            int m = c >> 4, nc = c & 15;
            u16x8 v = *(u16x8*)&smem[m * 128 + ((nc ^ (m & 15)) << 3)];
            *(u16x8*)&qo[(size_t)(bm * 128 + m) * H_ + bn * 128 + nc * 8] = v;
        }
    } else if (bn < 16) {
#pragma unroll
        for (int i = 0; i < 8; i++) {
            int c = i * 256 + tid;
            int si = c & 15, q = (c >> 4) & 3, hbl = (c >> 6) & 3, stl = c >> 8;
            int m = stl * 16 + si, nch = hbl * 4 + q;
            u16x8 v = *(u16x8*)&smem[m * 128 + ((nch ^ (m & 15)) << 3)];
            int stile = (bm & 15) * 8 + stl;
            int hb = (bn - 8) * 4 + hbl;
            *(u16x8*)&ko[(((size_t)b * 128 + stile) * 32 + hb) * 512 + q * 128 + si * 8] = v;
        }
    } else {
#pragma unroll
        for (int i = 0; i < 8; i++) {
            int c = i * 256 + tid;
            int hi = c & 15, q = (c >> 4) & 3, sbl = (c >> 6) & 3, hbl = c >> 8;
            int nl = hbl * 16 + hi, mch = sbl * 4 + q;
            u16x8 v = *(u16x8*)&smem[nl * 128 + ((mch ^ (nl & 15)) << 3)];
            int hb = (bn - 16) * 8 + hbl;
            int sb = (bm & 15) * 4 + sbl;
            *(u16x8*)&vo[(((size_t)b * 64 + hb) * 64 + sb) * 512 + q * 128 + hi * 8] = v;
        }
    }
}

// ---------------- flash attention v3 ----------------
// qb: row-major bf16 [B,T,H]; kf/vf: fragment-native; out fp32 [B,T,H]
#define INF __builtin_inff()
__global__ __launch_bounds__(512, 2) void attn(const u16* __restrict__ qb,
                                               const u16* __restrict__ kfg,
                                               const u16* __restrict__ vfg,
                                               float* __restrict__ out) {
    const int b = blockIdx.y;
    const int t0 = ((int)gridDim.x - 1 - (int)blockIdx.x) * 64;
    const int tid = threadIdx.x;
    const int w = tid >> 6, lane = tid & 63, quad = lane >> 4, l16 = lane & 15;
    const int srow = tid >> 3, sg = tid & 7;

    __shared__ u16 Qs[64 * 1024];     // 128 KB
    __shared__ float Ssm[64 * 128];   // 32 KB -> 160 KiB total

    u16* P = (u16*)Ssm;                                // bf16 [64][136]
    float* a_s = (float*)((char*)Ssm + 64 * 136 * 2);

    const u16* qB = qb + (size_t)b * T_ * H_;
    const u16* kfB = kfg + (size_t)b * 2097152;
    const u16* vfB = vfg + (size_t)b * 2097152;
    const float scale = 0.03125f;   // E^-0.5

#pragma unroll
    for (int i = 0; i < 16; i++) {
        int s = i * 512 + tid;
        int row = s >> 7, c2 = s & 127;
        int cc = c2 ^ (row & 7);
        gload_lds16(qB + (size_t)(t0 + row) * H_ + cc * 8, &Qs[s * 8]);
    }

    float m_r = -INF, l_r = 0.f;
    f32x4 o[32] = {};   // wave w owns H cols [w*128, w*128+128)
    const int mg = (w & 1) * 32, cg = (w >> 1) * 32;

    __syncthreads();   // Q staged

    for (int s0 = 0; s0 <= t0 + 63; s0 += 128) {
        // ---- phase 1: scores. wave computes S[mg..mg+32][cg..cg+32], 2x2 tiles
        f32x4 sc[2][2] = {{{}, {}}, {{}, {}}};
        {
            const u16* kp0 = kfB + ((size_t)((s0 >> 4) + (w >> 1) * 2) * 32) * 512 + lane * 8;
#pragma unroll 2
            for (int kk = 0; kk < H_; kk += 32) {
                bf16x8 kf0 = load_frag(kp0 + kk * 16);
                bf16x8 kf1 = load_frag(kp0 + 16384 + kk * 16);
                int kc8 = (kk >> 3) + quad;
#pragma unroll
                for (int mt2 = 0; mt2 < 2; mt2++) {
                    int row = mg + mt2 * 16 + l16;
                    bf16x8 af = load_frag(&Qs[(row * 128 + (kc8 ^ (row & 7))) * 8]);
                    sc[mt2][0] = __builtin_amdgcn_mfma_f32_16x16x32_bf16(af, kf0, sc[mt2][0], 0, 0, 0);
                    sc[mt2][1] = __builtin_amdgcn_mfma_f32_16x16x32_bf16(af, kf1, sc[mt2][1], 0, 0, 0);
                }
            }
        }
        __syncthreads();   // prev iteration's P/a_s reads complete
        {
#pragma unroll
            for (int mt2 = 0; mt2 < 2; mt2++)
#pragma unroll
                for (int ct2 = 0; ct2 < 2; ct2++)
#pragma unroll
                    for (int r = 0; r < 4; r++) {
                        int row = mg + mt2 * 16 + quad * 4 + r;
                        int col = cg + ct2 * 16 + l16;
                        int g2 = (col >> 2) ^ (row & 7);
                        Ssm[row * 128 + g2 * 4 + (col & 3)] =
                            (s0 + col <= t0 + row) ? sc[mt2][ct2][r] * scale : -INF;
                    }
        }
        __syncthreads();   // scores visible

        // ---- phase 2: online softmax (row srow, 8 threads/row)
        float vv[16];
#pragma unroll
        for (int i4 = 0; i4 < 4; i4++) {
            int g2 = (sg * 4 + i4) ^ (srow & 7);
            f32x4 t = *(const f32x4*)&Ssm[srow * 128 + g2 * 4];
            vv[i4 * 4 + 0] = t[0]; vv[i4 * 4 + 1] = t[1];
            vv[i4 * 4 + 2] = t[2]; vv[i4 * 4 + 3] = t[3];
        }
        float rmax = vv[0];
#pragma unroll
        for (int i = 1; i < 16; i++) rmax = fmaxf(rmax, vv[i]);
#pragma unroll
        for (int off = 4; off >= 1; off >>= 1) rmax = fmaxf(rmax, __shfl_xor(rmax, off, 64));
        float mn = fmaxf(m_r, rmax);
        float alpha = __expf(m_r - mn);
        float rsum = 0.f;
        u16x8 pl, ph;
#pragma unroll
        for (int i = 0; i < 8; i++) {
            float p = __expf(vv[i] - mn);
            rsum += p; pl[i] = f2bf(p);
        }
#pragma unroll
        for (int i = 0; i < 8; i++) {
            float p = __expf(vv[8 + i] - mn);
            rsum += p; ph[i] = f2bf(p);
        }
#pragma unroll
        for (int off = 4; off >= 1; off >>= 1) rsum += __shfl_xor(rsum, off, 64);
        l_r = l_r * alpha + rsum;
        m_r = mn;
        __syncthreads();   // score reads done before P overwrites Ssm
        *(u16x8*)&P[srow * 136 + sg * 16] = pl;
        *(u16x8*)&P[srow * 136 + sg * 16 + 8] = ph;
        if (sg == 0) a_s[srow] = alpha;
        __syncthreads();   // P + a_s visible

        // ---- phase 3: PV
        {
#pragma unroll
            for (int mt = 0; mt < 4; mt++) {
#pragma unroll
                for (int r = 0; r < 4; r++) {
                    float al = a_s[mt * 16 + quad * 4 + r];
#pragma unroll
                    for (int ht = 0; ht < 8; ht++) o[mt * 8 + ht][r] *= al;
                }
            }
            const u16* vpb = vfB + ((size_t)(s0 >> 5)) * 512 + lane * 8;
#pragma unroll
            for (int kc = 0; kc < 4; kc++) {
                bf16x8 pa[4];
#pragma unroll
                for (int mt = 0; mt < 4; mt++)
                    pa[mt] = load_frag(&P[(mt * 16 + l16) * 136 + kc * 32 + quad * 8]);
#pragma unroll
                for (int ht = 0; ht < 8; ht++) {
                    bf16x8 vfr = load_frag(vpb + (size_t)(w * 8 + ht) * 32768 + kc * 512);
#pragma unroll
                    for (int mt = 0; mt < 4; mt++)
                        o[mt * 8 + ht] = __builtin_amdgcn_mfma_f32_16x16x32_bf16(
                            pa[mt], vfr, o[mt * 8 + ht], 0, 0, 0);
                }
            }
        }
    }

    // ---- epilogue
    __syncthreads();
    if (sg == 0) a_s[srow] = l_r;
    __syncthreads();
    float* ob = out + (size_t)b * T_ * H_;
#pragma unroll
    for (int mt = 0; mt < 4; mt++) {
#pragma unroll
        for (int r = 0; r < 4; r++) {
            float linv = 1.f / a_s[mt * 16 + quad * 4 + r];
            int row = t0 + mt * 16 + quad * 4 + r;
#pragma unroll
            for (int ht = 0; ht < 8; ht++) {
                int col = w * 128 + ht * 16 + l16;
                ob[(size_t)row * H_ + col] = o[mt * 8 + ht][r] * linv;
            }
        }
    }
}

extern "C" void kernel_launch(void* const* d_in, const int* in_sizes, int n_in,
                              void* d_out, int out_size, void* d_ws, size_t ws_size,
                              hipStream_t stream) {
    const float* x  = (const float*)d_in[0];
    const float* Wk = (const float*)d_in[1];
    const float* Wq = (const float*)d_in[2];
    const float* Wv = (const float*)d_in[3];
    float* out = (float*)d_out;

    char* ws = (char*)d_ws;
    const size_t SZ_XB  = (size_t)M_ * E_ * 2;
    const size_t SZ_W   = (size_t)3 * H_ * E_ * 2;
    const size_t SZ_QKV = (size_t)M_ * H_ * 2;
    u16* xb   = (u16*)(ws);
    u16* wqkv = (u16*)(ws + SZ_XB);
    u16* qb   = (u16*)(ws + SZ_XB + SZ_W);
    u16* kfb  = (u16*)(ws + SZ_XB + SZ_W + SZ_QKV);
    u16* vfb  = (u16*)(ws + SZ_XB + SZ_W + 2 * SZ_QKV);

    castk<<<M_ * E_ / 4 / 256, 256, 0, stream>>>(x, xb, M_ * E_);
    castk<<<H_ * E_ / 4 / 256, 256, 0, stream>>>(Wq, wqkv, H_ * E_);
    castk<<<H_ * E_ / 4 / 256, 256, 0, stream>>>(Wk, wqkv + (size_t)H_ * E_, H_ * E_);
    castk<<<H_ * E_ / 4 / 256, 256, 0, stream>>>(Wv, wqkv + (size_t)2 * H_ * E_, H_ * E_);

    gemm_qkv<<<dim3(M_ / 128, 3072 / 128), 256, 0, stream>>>(xb, wqkv, qb, kfb, vfb);

    attn<<<dim3(T_ / 64, B_), 512, 0, stream>>>(qb, kfb, vfb, out);
}

// Round 4
// 541.418 us; speedup vs baseline: 1.1305x; 1.1305x over previous
//
#include <hip/hip_runtime.h>
#include <hip/hip_bf16.h>

typedef unsigned short u16;
typedef __bf16 bf16x8 __attribute__((ext_vector_type(8)));
typedef unsigned short u16x8 __attribute__((ext_vector_type(8)));
typedef unsigned short u16x4 __attribute__((ext_vector_type(4)));
typedef float f32x4 __attribute__((ext_vector_type(4)));
typedef float f32x16 __attribute__((ext_vector_type(16)));

#define B_ 8
#define T_ 2048
#define E_ 1024
#define H_ 1024
#define M_ (B_ * T_)   // 16384
#define INF __builtin_inff()

__device__ inline u16 f2bf(float f) {
    __bf16 h = (__bf16)f;
    return __builtin_bit_cast(u16, h);
}
__device__ inline float bf2f(u16 u) {
    unsigned v = (unsigned)u << 16;
    return __builtin_bit_cast(float, v);
}
__device__ inline bf16x8 load_frag(const u16* p) {
    u16x8 u = *(const u16x8*)p;
    return __builtin_bit_cast(bf16x8, u);
}
__device__ inline void gload_lds16(const u16* g, u16* l) {
    __builtin_amdgcn_global_load_lds(
        (__attribute__((address_space(1))) unsigned int*)(g),
        (__attribute__((address_space(3))) unsigned int*)(l), 16, 0, 0);
}

// ---------------- cast fp32 -> bf16 ----------------
__global__ void castk(const float* __restrict__ in, u16* __restrict__ out, int n) {
    int i = (blockIdx.x * blockDim.x + threadIdx.x) * 4;
    if (i < n) {
        f32x4 f = *(const f32x4*)(in + i);
        u16x4 u;
        u[0] = f2bf(f[0]); u[1] = f2bf(f[1]); u[2] = f2bf(f[2]); u[3] = f2bf(f[3]);
        *(u16x4*)(out + i) = u;
    }
}

// ---------------- fused QKV GEMM ----------------
// A: [16384][1024] bf16, W: [3072][1024] bf16 ([Wq;Wk;Wv])
// qo: row-major [M][1024]
// ko: frag-native for 32x32x16 B (n=s,k=h): [b][s/32][h/16][lane][8], lane: n=l&31, k=(l>>5)*8+j
// vo: frag-native for 32x32x16 B (n=h,k=s): [b][h/32][s/16][lane][8]
__global__ __launch_bounds__(256) void gemm_qkv(const u16* __restrict__ A,
                                                const u16* __restrict__ W,
                                                u16* __restrict__ qo,
                                                u16* __restrict__ ko,
                                                u16* __restrict__ vo) {
    const int bm = blockIdx.x, bn = blockIdx.y;
    const int tid = threadIdx.x;
    const int w = tid >> 6, lane = tid & 63, quad = lane >> 4, l16 = lane & 15;
    const int wr = w & 1, wc = w >> 1;

    __shared__ u16 smem[128 * 128];
    u16* As = smem;
    u16* Bs = smem + 128 * 64;

    f32x4 acc[16] = {};

    const u16* Ab = A + (size_t)(bm * 128) * E_;
    const u16* Wb = W + (size_t)(bn * 128) * E_;

    for (int kk = 0; kk < E_; kk += 64) {
        __syncthreads();
#pragma unroll
        for (int i = 0; i < 4; i++) {
            int chunk = i * 256 + tid;
            int row = chunk >> 3, cc = chunk & 7;
            int ccs = cc ^ (row & 7);
            gload_lds16(Ab + (size_t)row * E_ + kk + ccs * 8, &As[chunk * 8]);
            gload_lds16(Wb + (size_t)row * E_ + kk + ccs * 8, &Bs[chunk * 8]);
        }
        __syncthreads();
#pragma unroll
        for (int k2 = 0; k2 < 2; k2++) {
            bf16x8 af[4], bf[4];
#pragma unroll
            for (int ri = 0; ri < 4; ri++) {
                int m = wr * 64 + ri * 16 + l16;
                int slot = m * 8 + ((k2 * 4 + quad) ^ (m & 7));
                af[ri] = load_frag(&As[slot * 8]);
            }
#pragma unroll
            for (int ci = 0; ci < 4; ci++) {
                int n = wc * 64 + ci * 16 + l16;
                int slot = n * 8 + ((k2 * 4 + quad) ^ (n & 7));
                bf[ci] = load_frag(&Bs[slot * 8]);
            }
#pragma unroll
            for (int ri = 0; ri < 4; ri++)
#pragma unroll
                for (int ci = 0; ci < 4; ci++)
                    acc[ri * 4 + ci] = __builtin_amdgcn_mfma_f32_16x16x32_bf16(
                        af[ri], bf[ci], acc[ri * 4 + ci], 0, 0, 0);
        }
    }

    // ---- epilogue: acc -> LDS bf16 (swizzled) -> coalesced stores ----
    __syncthreads();
    if (bn < 16) {
        // [m][n]: elem(m,n) @ m*128 + ((n>>3 ^ (m&15))<<3) + (n&7)
#pragma unroll
        for (int ri = 0; ri < 4; ri++)
#pragma unroll
            for (int ci = 0; ci < 4; ci++) {
                int n = wc * 64 + ci * 16 + l16;
#pragma unroll
                for (int r = 0; r < 4; r++) {
                    int m = wr * 64 + ri * 16 + quad * 4 + r;
                    smem[m * 128 + (((n >> 3) ^ (m & 15)) << 3) + (n & 7)] =
                        f2bf(acc[ri * 4 + ci][r]);
                }
            }
    } else {
        // [n][m], pack 4 consecutive m
#pragma unroll
        for (int ri = 0; ri < 4; ri++)
#pragma unroll
            for (int ci = 0; ci < 4; ci++) {
                int n = wc * 64 + ci * 16 + l16;
                int m0 = wr * 64 + ri * 16 + quad * 4;
                u16x4 pk;
#pragma unroll
                for (int r = 0; r < 4; r++) pk[r] = f2bf(acc[ri * 4 + ci][r]);
                *(u16x4*)&smem[n * 128 + (((m0 >> 3) ^ (n & 15)) << 3) + (m0 & 7)] = pk;
            }
    }
    __syncthreads();

    const int b = bm >> 4;
    if (bn < 8) {
#pragma unroll
        for (int i = 0; i < 8; i++) {
            int c = i * 256 + tid;
            int m = c >> 4, nc = c & 15;
            u16x8 v = *(u16x8*)&smem[m * 128 + ((nc ^ (m & 15)) << 3)];
            *(u16x8*)&qo[(size_t)(bm * 128 + m) * H_ + bn * 128 + nc * 8] = v;
        }
    } else if (bn < 16) {
        // K frag-native: chunk = (s fixed, 8 consecutive h) from [m=s][n=h] tile
#pragma unroll
        for (int i = 0; i < 8; i++) {
            int c = i * 256 + tid;
            int ln = c & 63, h16c = (c >> 6) & 7, s32c = c >> 9;
            int m = s32c * 32 + (ln & 31);
            int nc = h16c * 2 + (ln >> 5);
            u16x8 v = *(u16x8*)&smem[m * 128 + ((nc ^ (m & 15)) << 3)];
            int s32g = (bm & 15) * 4 + s32c;
            int h16g = (bn - 8) * 8 + h16c;
            *(u16x8*)&ko[(((size_t)b * 64 + s32g) * 64 + h16g) * 512 + ln * 8] = v;
        }
    } else {
        // V frag-native: chunk = (h fixed, 8 consecutive s) from [n=h][m=s] tile
#pragma unroll
        for (int i = 0; i < 8; i++) {
            int c = i * 256 + tid;
            int ln = c & 63, s16c = (c >> 6) & 7, h32c = c >> 9;
            int n = h32c * 32 + (ln & 31);
            int mc = s16c * 2 + (ln >> 5);
            u16x8 v = *(u16x8*)&smem[n * 128 + ((mc ^ (n & 15)) << 3)];
            int h32g = (bn - 16) * 4 + h32c;
            int s16g = (bm & 15) * 8 + s16c;
            *(u16x8*)&vo[(((size_t)b * 32 + h32g) * 128 + s16g) * 512 + ln * 8] = v;
        }
    }
}

// ---------------- flash attention v4: 32x32x16 MFMA, k-split, no dup ----------------
// 64 q-rows/block, 8 waves. LDS = Qs 128K + 2x16K bf16 S-partials = 160 KiB.
__global__ __launch_bounds__(512, 2) void attn(const u16* __restrict__ qb,
                                               const u16* __restrict__ kfg,
                                               const u16* __restrict__ vfg,
                                               float* __restrict__ out) {
    const int b = blockIdx.y;
    const int t0 = ((int)gridDim.x - 1 - (int)blockIdx.x) * 64;
    const int tid = threadIdx.x;
    const int w = tid >> 6, lane = tid & 63;
    const int l5 = lane >> 5, l31 = lane & 31;
    const int srow = tid >> 3, sg = tid & 7;

    __shared__ u16 Qs[64 * 1024];   // 128 KB, [row][chunk ^ (row&7)]
    __shared__ u16 Sp[2 * 64 * 128]; // 32 KB: two bf16 [64][128] partials (chunk-swizzled)
    float* alphas = (float*)(Sp + 8192);  // aliases Sp1[0..255B]; written after Sp1 reads

    const u16* qB = qb + (size_t)b * T_ * H_;
    const u16* kfB = kfg + (size_t)b * 2097152;
    const u16* vfB = vfg + (size_t)b * 2097152;
    const float scale = 0.03125f;   // E^-0.5

    // stage Q
#pragma unroll
    for (int i = 0; i < 16; i++) {
        int s = i * 512 + tid;
        int row = s >> 7, c = s & 127;
        int cc = c ^ (row & 7);
        gload_lds16(qB + (size_t)(t0 + row) * H_ + cc * 8, &Qs[s * 8]);
    }

    float m_r = -INF, l_r = 0.f;
    f32x16 o[2][4] = {};   // [rowgroup][h-tile]; wave w: H cols [w*128, w*128+128)

    const int ct = w & 3;        // S col-tile (32 cols)
    const int kh = w >> 2;       // k-half

    __syncthreads();   // Q staged

    for (int s0 = 0; s0 <= t0 + 63; s0 += 128) {
        // ---- phase 1: partial scores, wave: cols ct*32..+32, k in [kh*512, kh*512+512)
        f32x16 sa0 = {}, sa1 = {};
        {
            const u16* kp = kfB + (((size_t)((s0 >> 5) + ct)) * 64 + kh * 32) * 512 + lane * 8;
#pragma unroll 8
            for (int st = 0; st < 32; st++) {
                bf16x8 kf = load_frag(kp + st * 512);
                int cb = (kh * 32 + st) * 2 + l5;
                int x0 = l31 & 7;   // (32+l31)&7 == l31&7
                bf16x8 a0 = load_frag(&Qs[((size_t)l31 * 128 + (cb ^ x0)) * 8]);
                bf16x8 a1 = load_frag(&Qs[((size_t)(32 + l31) * 128 + (cb ^ x0)) * 8]);
                sa0 = __builtin_amdgcn_mfma_f32_32x32x16_bf16(a0, kf, sa0, 0, 0, 0);
                sa1 = __builtin_amdgcn_mfma_f32_32x32x16_bf16(a1, kf, sa1, 0, 0, 0);
            }
        }
        __syncthreads();   // prev PV done reading P(Sp0) + alphas(Sp1)
        {
            u16* Sdst = Sp + kh * 8192;
            int col = ct * 32 + l31;
            int chc = col >> 3, cil = col & 7;
#pragma unroll
            for (int reg = 0; reg < 16; reg++) {
                int row = (reg & 3) + 8 * (reg >> 2) + 4 * l5;
                Sdst[(row * 16 + (chc ^ (row & 7))) * 8 + cil] = f2bf(sa0[reg] * scale);
                int row1 = row + 32;
                Sdst[(row1 * 16 + (chc ^ (row1 & 7))) * 8 + cil] = f2bf(sa1[reg] * scale);
            }
        }
        __syncthreads();   // partials visible

        // ---- phase 2: softmax. thread (srow, sg): cols sg*16..+16
        {
            int sw0 = (sg * 2) ^ (srow & 7), sw1 = (sg * 2 + 1) ^ (srow & 7);
            u16x8 a0 = *(u16x8*)&Sp[(srow * 16 + sw0) * 8];
            u16x8 a1 = *(u16x8*)&Sp[(srow * 16 + sw1) * 8];
            u16x8 b0 = *(u16x8*)&Sp[8192 + (srow * 16 + sw0) * 8];
            u16x8 b1 = *(u16x8*)&Sp[8192 + (srow * 16 + sw1) * 8];
            float v[16];
#pragma unroll
            for (int j = 0; j < 8; j++) v[j] = bf2f(a0[j]) + bf2f(b0[j]);
#pragma unroll
            for (int j = 0; j < 8; j++) v[8 + j] = bf2f(a1[j]) + bf2f(b1[j]);
            int colb = sg * 16;
#pragma unroll
            for (int j = 0; j < 16; j++)
                if (s0 + colb + j > t0 + srow) v[j] = -INF;
            float rmax = v[0];
#pragma unroll
            for (int j = 1; j < 16; j++) rmax = fmaxf(rmax, v[j]);
#pragma unroll
            for (int off = 4; off >= 1; off >>= 1) rmax = fmaxf(rmax, __shfl_xor(rmax, off, 64));
            float mn = fmaxf(m_r, rmax);
            float alpha = __expf(m_r - mn);
            float rsum = 0.f;
            u16x8 p0, p1;
#pragma unroll
            for (int j = 0; j < 8; j++) {
                float p = __expf(v[j] - mn);
                rsum += p; p0[j] = f2bf(p);
            }
#pragma unroll
            for (int j = 0; j < 8; j++) {
                float p = __expf(v[8 + j] - mn);
                rsum += p; p1[j] = f2bf(p);
            }
#pragma unroll
            for (int off = 4; off >= 1; off >>= 1) rsum += __shfl_xor(rsum, off, 64);
            l_r = l_r * alpha + rsum;
            m_r = mn;
            // P in-place over the exact slots this thread read from Sp0
            *(u16x8*)&Sp[(srow * 16 + sw0) * 8] = p0;
            *(u16x8*)&Sp[(srow * 16 + sw1) * 8] = p1;
            __syncthreads();   // all Sp1 reads done
            if (sg == 0) alphas[srow] = alpha;
        }
        __syncthreads();   // P + alphas visible

        // ---- phase 3: PV. wave w: h cols w*128..+128, all 64 rows
        {
#pragma unroll
            for (int rg = 0; rg < 2; rg++)
#pragma unroll
                for (int reg = 0; reg < 16; reg++) {
                    float al = alphas[rg * 32 + (reg & 3) + 8 * (reg >> 2) + 4 * l5];
#pragma unroll
                    for (int ht = 0; ht < 4; ht++) o[rg][ht][reg] *= al;
                }
            const u16* vp = vfB + ((size_t)(w * 4) * 128 + (s0 >> 4)) * 512 + lane * 8;
            int xp = l31 & 7;
#pragma unroll
            for (int sc = 0; sc < 8; sc++) {
                bf16x8 p0 = load_frag(&Sp[((size_t)l31 * 16 + ((sc * 2 + l5) ^ xp)) * 8]);
                bf16x8 p1 = load_frag(&Sp[((size_t)(32 + l31) * 16 + ((sc * 2 + l5) ^ xp)) * 8]);
#pragma unroll
                for (int ht = 0; ht < 4; ht++) {
                    bf16x8 vv = load_frag(vp + ((size_t)ht * 128 + sc) * 512);
                    o[0][ht] = __builtin_amdgcn_mfma_f32_32x32x16_bf16(p0, vv, o[0][ht], 0, 0, 0);
                    o[1][ht] = __builtin_amdgcn_mfma_f32_32x32x16_bf16(p1, vv, o[1][ht], 0, 0, 0);
                }
            }
        }
    }

    // ---- epilogue
    __syncthreads();
    if (sg == 0) alphas[srow] = l_r;
    __syncthreads();
    float* ob = out + (size_t)b * T_ * H_;
#pragma unroll
    for (int rg = 0; rg < 2; rg++)
#pragma unroll
        for (int reg = 0; reg < 16; reg++) {
            int row = rg * 32 + (reg & 3) + 8 * (reg >> 2) + 4 * l5;
            float linv = 1.f / alphas[row];
#pragma unroll
            for (int ht = 0; ht < 4; ht++) {
                int col = w * 128 + ht * 32 + l31;
                ob[(size_t)(t0 + row) * H_ + col] = o[rg][ht][reg] * linv;
            }
        }
}

extern "C" void kernel_launch(void* const* d_in, const int* in_sizes, int n_in,
                              void* d_out, int out_size, void* d_ws, size_t ws_size,
                              hipStream_t stream) {
    const float* x  = (const float*)d_in[0];
    const float* Wk = (const float*)d_in[1];
    const float* Wq = (const float*)d_in[2];
    const float* Wv = (const float*)d_in[3];
    float* out = (float*)d_out;

    char* ws = (char*)d_ws;
    const size_t SZ_XB  = (size_t)M_ * E_ * 2;
    const size_t SZ_W   = (size_t)3 * H_ * E_ * 2;
    const size_t SZ_QKV = (size_t)M_ * H_ * 2;
    u16* xb   = (u16*)(ws);
    u16* wqkv = (u16*)(ws + SZ_XB);
    u16* qb   = (u16*)(ws + SZ_XB + SZ_W);
    u16* kfb  = (u16*)(ws + SZ_XB + SZ_W + SZ_QKV);
    u16* vfb  = (u16*)(ws + SZ_XB + SZ_W + 2 * SZ_QKV);

    castk<<<M_ * E_ / 4 / 256, 256, 0, stream>>>(x, xb, M_ * E_);
    castk<<<H_ * E_ / 4 / 256, 256, 0, stream>>>(Wq, wqkv, H_ * E_);
    castk<<<H_ * E_ / 4 / 256, 256, 0, stream>>>(Wk, wqkv + (size_t)H_ * E_, H_ * E_);
    castk<<<H_ * E_ / 4 / 256, 256, 0, stream>>>(Wv, wqkv + (size_t)2 * H_ * E_, H_ * E_);

    gemm_qkv<<<dim3(M_ / 128, 3072 / 128), 256, 0, stream>>>(xb, wqkv, qb, kfb, vfb);

    attn<<<dim3(T_ / 64, B_), 512, 0, stream>>>(qb, kfb, vfb, out);
}